// Round 12
// baseline (151.583 us; speedup 1.0000x reference)
//
#include <hip/hip_runtime.h>

#define CONS_RATE 0.001f
#define CLAMP_V   10.0f

// e^(2s) = 2^(s * 2/ln2)
#define TWO_LOG2E 2.88539008177792681472f

#if defined(__has_builtin)
#  if __has_builtin(__builtin_amdgcn_exp2f)
#    define EXP2F(x) __builtin_amdgcn_exp2f(x)
#  endif
#endif
#ifndef EXP2F
#  define EXP2F(x) __expf(0.69314718055994530942f * (x))
#endif

typedef float f32x4 __attribute__((ext_vector_type(4)));

__device__ __forceinline__ float rf(float x) {
    return __uint_as_float(__builtin_amdgcn_readfirstlane(__float_as_uint(x)));
}

// ---------------------------------------------------------------------------
// DIAGNOSTIC DISPATCH 1: pure copy probe (m13 pattern: float4, grid-stride,
// 2048x256, nt load+store, zero compute). Measures THIS harness's achievable
// read+write floor for the exact buffers/size the real kernel touches.
// Its output is garbage-equivalent (raw w) and is FULLY OVERWRITTEN by the
// real kernel that follows, so end-to-end results remain exact.
// ---------------------------------------------------------------------------
__global__ __launch_bounds__(256) void CD_memfloor_probe_kernel(
    const float* __restrict__ in, float* __restrict__ outp, int n4)
{
    const f32x4* __restrict__ w4 = (const f32x4*)in;
    f32x4* __restrict__ o4 = (f32x4*)outp;
    const int nth = gridDim.x * blockDim.x;
    for (int i = blockIdx.x * blockDim.x + threadIdx.x; i < n4; i += nth) {
        const f32x4 v = __builtin_nontemporal_load(&w4[i]);
        __builtin_nontemporal_store(v, &o4[i]);
    }
}

// ---------------------------------------------------------------------------
// DISPATCH 2: the exact kernel (round-5 one-shot, abs-identity form).
//   out = clamp(w + 0.001*tanh(P + Q*w + sum_j u_j*|w - t_j|))
// ---------------------------------------------------------------------------
__global__ __launch_bounds__(256) void ConsolidationDynamics_70068096467285_kernel(
    const float* __restrict__ w,
    const float* __restrict__ cs_p,
    const float* __restrict__ fs_p,
    const float* __restrict__ W1,   // (3,16) row-major
    const float* __restrict__ b1,   // (16,)
    const float* __restrict__ W2,   // (16,1)
    const float* __restrict__ b2,   // (1,)
    float* __restrict__ out,
    int n)
{
    const float cs = cs_p[0];
    const float fs = fs_p[0];

    float P = b2[0];
    float Q = 0.0f;

#define COEF(J) \
    float t##J, u##J; { \
        const float a = W1[J]; \
        const float v = W2[J]; \
        const float c = fmaf(cs, W1[16 + J], fmaf(fs, W1[32 + J], b1[J])); \
        P = fmaf(0.5f * v, c, P); \
        Q = fmaf(0.5f * v, a, Q); \
        if (a != 0.0f) { t##J = rf(-c / a); u##J = rf(0.5f * v * fabsf(a)); } \
        else { t##J = 0.0f; u##J = 0.0f; P = fmaf(v, fmaxf(c, 0.0f) - 0.5f * c, P); } \
    }
    COEF(0)  COEF(1)  COEF(2)  COEF(3)
    COEF(4)  COEF(5)  COEF(6)  COEF(7)
    COEF(8)  COEF(9)  COEF(10) COEF(11)
    COEF(12) COEF(13) COEF(14) COEF(15)
#undef COEF
    P = rf(P);
    Q = rf(Q);

#define TERM(J, sacc) sacc = fmaf(u##J, fabsf(t##J - r_), sacc);

#define EVAL(rr, d) { \
    const float r_ = (rr); \
    float s0 = fmaf(r_, Q, P); \
    float s1 = u1 * fabsf(t1 - r_); \
    TERM(0, s0)  TERM(2, s0)  TERM(3, s1)  TERM(4, s0)  TERM(5, s1) \
    TERM(6, s0)  TERM(7, s1)  TERM(8, s0)  TERM(9, s1)  TERM(10, s0) \
    TERM(11, s1) TERM(12, s0) TERM(13, s1) TERM(14, s0) TERM(15, s1) \
    const float e  = EXP2F((s0 + s1) * TWO_LOG2E); \
    const float u  = fmaf(-2.0f, __builtin_amdgcn_rcpf(e + 1.0f), 1.0f); \
    const float nw = fmaf(u, CONS_RATE, r_); \
    (d) = fminf(fmaxf(nw, -CLAMP_V), CLAMP_V); }

#define EVAL4(V, O) \
    EVAL((V).x, (O).x) EVAL((V).y, (O).y) EVAL((V).z, (O).z) EVAL((V).w, (O).w)

    const int n4 = n >> 2;
    const f32x4* __restrict__ w4 = (const f32x4*)w;
    f32x4* __restrict__ o4 = (f32x4*)out;

    const int tid  = threadIdx.x;
    const int base = blockIdx.x * 1024 + tid;
    const int i0 = base, i1 = base + 256, i2 = base + 512, i3 = base + 768;

    if (i3 < n4) {
        const f32x4 A = w4[i0];
        const f32x4 B = w4[i1];
        const f32x4 C = w4[i2];
        const f32x4 D = w4[i3];
        f32x4 oA, oB, oC, oD;
        EVAL4(A, oA) EVAL4(B, oB) EVAL4(C, oC) EVAL4(D, oD)
        __builtin_nontemporal_store(oA, &o4[i0]);
        __builtin_nontemporal_store(oB, &o4[i1]);
        __builtin_nontemporal_store(oC, &o4[i2]);
        __builtin_nontemporal_store(oD, &o4[i3]);
    } else {
        for (int k = 0; k < 4; ++k) {
            const int idx = base + (k << 8);
            if (idx < n4) {
                const f32x4 A = w4[idx];
                f32x4 oA;
                EVAL4(A, oA)
                __builtin_nontemporal_store(oA, &o4[idx]);
            }
        }
    }
    // Scalar tail (n % 4), block 0.
    if (blockIdx.x == 0) {
        const int rem = n & 3;
        if (tid < rem) {
            const float r = w[(n4 << 2) + tid];
            float d;
            EVAL(r, d)
            out[(n4 << 2) + tid] = d;
        }
    }
#undef EVAL4
#undef EVAL
#undef TERM
}

extern "C" void kernel_launch(void* const* d_in, const int* in_sizes, int n_in,
                              void* d_out, int out_size, void* d_ws, size_t ws_size,
                              hipStream_t stream) {
    const float* w   = (const float*)d_in[0];
    const float* cs  = (const float*)d_in[1];
    const float* fs  = (const float*)d_in[2];
    const float* W1  = (const float*)d_in[3];
    const float* b1  = (const float*)d_in[4];
    const float* W2  = (const float*)d_in[5];
    const float* b2  = (const float*)d_in[6];
    float* out = (float*)d_out;

    const int n  = in_sizes[0];
    const int n4 = n >> 2;

    // Dispatch 1: memory-floor probe (m13 copy pattern). Output is fully
    // overwritten by dispatch 2 -> end result exact. The probe's time shows
    // up as (dur_us - ~124.5); if >41us it also appears in top-5 counters.
    CD_memfloor_probe_kernel<<<2048, 256, 0, stream>>>(w, out, n4);

    // Dispatch 2: exact kernel (round-5 one-shot).
    const int block = 256;
    int grid = (n4 + 1023) >> 10;
    if (grid < 1) grid = 1;
    ConsolidationDynamics_70068096467285_kernel<<<grid, block, 0, stream>>>(
        w, cs, fs, W1, b1, W2, b2, out, n);
}

// Round 13
// 133.999 us; speedup vs baseline: 1.1312x; 1.1312x over previous
//
#include <hip/hip_runtime.h>

#define CONS_RATE 0.001f
#define CLAMP_V   10.0f

// e^(2s) = 2^(s * 2/ln2)
#define TWO_LOG2E 2.88539008177792681472f

#if defined(__has_builtin)
#  if __has_builtin(__builtin_amdgcn_exp2f)
#    define EXP2F(x) __builtin_amdgcn_exp2f(x)
#  endif
#endif
#ifndef EXP2F
#  define EXP2F(x) __expf(0.69314718055994530942f * (x))
#endif

typedef float f32x4 __attribute__((ext_vector_type(4)));

__device__ __forceinline__ float rf(float x) {
    return __uint_as_float(__builtin_amdgcn_readfirstlane(__float_as_uint(x)));
}

// Round-13: NONTEMPORAL LOADS. Round-12's probe measured the in-harness
// copy floor at ~27us (4.7 TB/s) using nt load + nt store; every ~40us
// kernel variant used CACHED loads. The LUT round exonerated VALU count;
// topology/occupancy/pipelining were exonerated earlier. The one untested
// axis was the load cache-op. Mechanism: nt loads bypass L2/L3 allocation,
// removing read-stream/write-stream cache interference. Signature to watch:
// FETCH_SIZE 32.8MB -> ~65MB (reads no longer L3-absorbed) + dur drop.
// Everything else is byte-identical to the round-5 kernel (one-shot,
// 4 coalesced float4/thread, abs-identity SGPR compute, nt stores).

__global__ __launch_bounds__(256) void ConsolidationDynamics_70068096467285_kernel(
    const float* __restrict__ w,
    const float* __restrict__ cs_p,
    const float* __restrict__ fs_p,
    const float* __restrict__ W1,   // (3,16) row-major
    const float* __restrict__ b1,   // (16,)
    const float* __restrict__ W2,   // (16,1)
    const float* __restrict__ b2,   // (1,)
    float* __restrict__ out,
    int n)
{
    const float cs = cs_p[0];
    const float fs = fs_p[0];

    float P = b2[0];
    float Q = 0.0f;

#define COEF(J) \
    float t##J, u##J; { \
        const float a = W1[J]; \
        const float v = W2[J]; \
        const float c = fmaf(cs, W1[16 + J], fmaf(fs, W1[32 + J], b1[J])); \
        P = fmaf(0.5f * v, c, P); \
        Q = fmaf(0.5f * v, a, Q); \
        if (a != 0.0f) { t##J = rf(-c / a); u##J = rf(0.5f * v * fabsf(a)); } \
        else { t##J = 0.0f; u##J = 0.0f; P = fmaf(v, fmaxf(c, 0.0f) - 0.5f * c, P); } \
    }
    COEF(0)  COEF(1)  COEF(2)  COEF(3)
    COEF(4)  COEF(5)  COEF(6)  COEF(7)
    COEF(8)  COEF(9)  COEF(10) COEF(11)
    COEF(12) COEF(13) COEF(14) COEF(15)
#undef COEF
    P = rf(P);
    Q = rf(Q);

#define TERM(J, sacc) sacc = fmaf(u##J, fabsf(t##J - r_), sacc);

#define EVAL(rr, d) { \
    const float r_ = (rr); \
    float s0 = fmaf(r_, Q, P); \
    float s1 = u1 * fabsf(t1 - r_); \
    TERM(0, s0)  TERM(2, s0)  TERM(3, s1)  TERM(4, s0)  TERM(5, s1) \
    TERM(6, s0)  TERM(7, s1)  TERM(8, s0)  TERM(9, s1)  TERM(10, s0) \
    TERM(11, s1) TERM(12, s0) TERM(13, s1) TERM(14, s0) TERM(15, s1) \
    const float e  = EXP2F((s0 + s1) * TWO_LOG2E); \
    const float u  = fmaf(-2.0f, __builtin_amdgcn_rcpf(e + 1.0f), 1.0f); \
    const float nw = fmaf(u, CONS_RATE, r_); \
    (d) = fminf(fmaxf(nw, -CLAMP_V), CLAMP_V); }

#define EVAL4(V, O) \
    EVAL((V).x, (O).x) EVAL((V).y, (O).y) EVAL((V).z, (O).z) EVAL((V).w, (O).w)

    const int n4 = n >> 2;
    const f32x4* __restrict__ w4 = (const f32x4*)w;
    f32x4* __restrict__ o4 = (f32x4*)out;

    const int tid  = threadIdx.x;
    const int base = blockIdx.x * 1024 + tid;
    const int i0 = base, i1 = base + 256, i2 = base + 512, i3 = base + 768;

    if (i3 < n4) {
        const f32x4 A = __builtin_nontemporal_load(&w4[i0]);
        const f32x4 B = __builtin_nontemporal_load(&w4[i1]);
        const f32x4 C = __builtin_nontemporal_load(&w4[i2]);
        const f32x4 D = __builtin_nontemporal_load(&w4[i3]);
        f32x4 oA, oB, oC, oD;
        EVAL4(A, oA) EVAL4(B, oB) EVAL4(C, oC) EVAL4(D, oD)
        __builtin_nontemporal_store(oA, &o4[i0]);
        __builtin_nontemporal_store(oB, &o4[i1]);
        __builtin_nontemporal_store(oC, &o4[i2]);
        __builtin_nontemporal_store(oD, &o4[i3]);
    } else {
        for (int k = 0; k < 4; ++k) {
            const int idx = base + (k << 8);
            if (idx < n4) {
                const f32x4 A = __builtin_nontemporal_load(&w4[idx]);
                f32x4 oA;
                EVAL4(A, oA)
                __builtin_nontemporal_store(oA, &o4[idx]);
            }
        }
    }
    // Scalar tail (n % 4), block 0.
    if (blockIdx.x == 0) {
        const int rem = n & 3;
        if (tid < rem) {
            const float r = w[(n4 << 2) + tid];
            float d;
            EVAL(r, d)
            out[(n4 << 2) + tid] = d;
        }
    }
#undef EVAL4
#undef EVAL
#undef TERM
}

extern "C" void kernel_launch(void* const* d_in, const int* in_sizes, int n_in,
                              void* d_out, int out_size, void* d_ws, size_t ws_size,
                              hipStream_t stream) {
    const float* w   = (const float*)d_in[0];
    const float* cs  = (const float*)d_in[1];
    const float* fs  = (const float*)d_in[2];
    const float* W1  = (const float*)d_in[3];
    const float* b1  = (const float*)d_in[4];
    const float* W2  = (const float*)d_in[5];
    const float* b2  = (const float*)d_in[6];
    float* out = (float*)d_out;

    const int n  = in_sizes[0];
    const int n4 = n >> 2;
    // Round-5 topology: one float4-quad (4096 elements) per 256-thread block.
    const int block = 256;
    int grid = (n4 + 1023) >> 10;
    if (grid < 1) grid = 1;

    ConsolidationDynamics_70068096467285_kernel<<<grid, block, 0, stream>>>(
        w, cs, fs, W1, b1, W2, b2, out, n);
}

// Round 14
// 124.896 us; speedup vs baseline: 1.2137x; 1.0729x over previous
//
#include <hip/hip_runtime.h>

#define CONS_RATE 0.001f
#define CLAMP_V   10.0f

// e^(2s) = 2^(s * 2/ln2)
#define TWO_LOG2E 2.88539008177792681472f

#if defined(__has_builtin)
#  if __has_builtin(__builtin_amdgcn_exp2f)
#    define EXP2F(x) __builtin_amdgcn_exp2f(x)
#  endif
#endif
#ifndef EXP2F
#  define EXP2F(x) __expf(0.69314718055994530942f * (x))
#endif

typedef float f32x4 __attribute__((ext_vector_type(4)));

__device__ __forceinline__ float rf(float x) {
    return __uint_as_float(__builtin_amdgcn_readfirstlane(__float_as_uint(x)));
}

// Round-14: WAVE SPECIALIZATION (producer-consumer via LDS).
// Evidence: T = T_mem + T_valu additive across ALL 13 prior variants
// (probe 27 = nt-copy no compute; +nt loads +9.4us = the L3-absorbed reads
// at 3.4 TB/s; cached+compute 40 = 18+22). Same-wave load->41op->store
// serializes memory and VALU device-wide. m114: separate waves' pipes
// co-schedule fully. So: 4 MEM waves/block stream HBM<->LDS (probe-like,
// ZERO dependent compute) while 4 CMP waves run LDS->EVAL->LDS.
// Double-buffered 2x(8KB in + 8KB out) = 32KB LDS; 1 barrier/chunk.

#define CHUNK_F4  512                    // float4 per chunk (8KB)
#define NCH       16                     // chunks per block
#define SLAB_F4   (CHUNK_F4 * NCH)       // 8192 float4 per block

__global__ __launch_bounds__(512) void ConsolidationDynamics_70068096467285_kernel(
    const float* __restrict__ w,
    const float* __restrict__ cs_p,
    const float* __restrict__ fs_p,
    const float* __restrict__ W1,   // (3,16) row-major
    const float* __restrict__ b1,   // (16,)
    const float* __restrict__ W2,   // (16,1)
    const float* __restrict__ b2,   // (1,)
    float* __restrict__ out,
    int n)
{
    __shared__ float s_in [2][CHUNK_F4 * 4];
    __shared__ float s_out[2][CHUNK_F4 * 4];

    const float cs = cs_p[0];
    const float fs = fs_p[0];

    float P = b2[0];
    float Q = 0.0f;

#define COEF(J) \
    float t##J, u##J; { \
        const float a = W1[J]; \
        const float v = W2[J]; \
        const float c = fmaf(cs, W1[16 + J], fmaf(fs, W1[32 + J], b1[J])); \
        P = fmaf(0.5f * v, c, P); \
        Q = fmaf(0.5f * v, a, Q); \
        if (a != 0.0f) { t##J = rf(-c / a); u##J = rf(0.5f * v * fabsf(a)); } \
        else { t##J = 0.0f; u##J = 0.0f; P = fmaf(v, fmaxf(c, 0.0f) - 0.5f * c, P); } \
    }
    COEF(0)  COEF(1)  COEF(2)  COEF(3)
    COEF(4)  COEF(5)  COEF(6)  COEF(7)
    COEF(8)  COEF(9)  COEF(10) COEF(11)
    COEF(12) COEF(13) COEF(14) COEF(15)
#undef COEF
    P = rf(P);
    Q = rf(Q);

#define TERM(J, sacc) sacc = fmaf(u##J, fabsf(t##J - r_), sacc);

#define EVAL(rr, d) { \
    const float r_ = (rr); \
    float s0 = fmaf(r_, Q, P); \
    float s1 = u1 * fabsf(t1 - r_); \
    TERM(0, s0)  TERM(2, s0)  TERM(3, s1)  TERM(4, s0)  TERM(5, s1) \
    TERM(6, s0)  TERM(7, s1)  TERM(8, s0)  TERM(9, s1)  TERM(10, s0) \
    TERM(11, s1) TERM(12, s0) TERM(13, s1) TERM(14, s0) TERM(15, s1) \
    const float e  = EXP2F((s0 + s1) * TWO_LOG2E); \
    const float u  = fmaf(-2.0f, __builtin_amdgcn_rcpf(e + 1.0f), 1.0f); \
    const float nw = fmaf(u, CONS_RATE, r_); \
    (d) = fminf(fmaxf(nw, -CLAMP_V), CLAMP_V); }

#define EVAL4(V, O) \
    EVAL((V).x, (O).x) EVAL((V).y, (O).y) EVAL((V).z, (O).z) EVAL((V).w, (O).w)

    const int n4 = n >> 2;
    const f32x4* __restrict__ gin = (const f32x4*)w;
    f32x4* __restrict__ gout = (f32x4*)out;

    const int tid   = threadIdx.x;
    const int slab4 = blockIdx.x * SLAB_F4;      // float4 index of block slab

    if (slab4 + SLAB_F4 <= n4) {
        // ---------- full-slab pipelined path ----------
        const bool is_mem = tid < 256;           // waves 0-3 = MEM, 4-7 = CMP

        if (is_mem) {
            // Prologue: load chunk 0 (cached loads: L3 hits are real wins).
            const f32x4 a0 = gin[slab4 + tid];
            const f32x4 a1 = gin[slab4 + tid + 256];
            *(f32x4*)&s_in[0][4 * tid]         = a0;
            *(f32x4*)&s_in[0][4 * (tid + 256)] = a1;
        }
        __syncthreads();

        for (int c = 0; c < NCH; ++c) {
            if (is_mem) {
                if (c > 0) {
                    // store chunk c-1 (computed last iter)
                    const int pb = (c - 1) & 1;
                    const int o4 = slab4 + (c - 1) * CHUNK_F4 + tid;
                    const f32x4 r0 = *(const f32x4*)&s_out[pb][4 * tid];
                    const f32x4 r1 = *(const f32x4*)&s_out[pb][4 * (tid + 256)];
                    __builtin_nontemporal_store(r0, &gout[o4]);
                    __builtin_nontemporal_store(r1, &gout[o4 + 256]);
                }
                if (c + 1 < NCH) {
                    // load chunk c+1
                    const int nb = (c + 1) & 1;
                    const int i4 = slab4 + (c + 1) * CHUNK_F4 + tid;
                    const f32x4 a0 = gin[i4];
                    const f32x4 a1 = gin[i4 + 256];
                    *(f32x4*)&s_in[nb][4 * tid]         = a0;
                    *(f32x4*)&s_in[nb][4 * (tid + 256)] = a1;
                }
            } else {
                // compute chunk c: LDS -> EVAL -> LDS (no global access)
                const int ct = tid - 256;
                const int b  = c & 1;
                const f32x4 A = *(const f32x4*)&s_in[b][4 * ct];
                const f32x4 B = *(const f32x4*)&s_in[b][4 * (ct + 256)];
                f32x4 oA, oB;
                EVAL4(A, oA) EVAL4(B, oB)
                *(f32x4*)&s_out[b][4 * ct]         = oA;
                *(f32x4*)&s_out[b][4 * (ct + 256)] = oB;
            }
            __syncthreads();
        }
        if (is_mem) {
            // Epilogue: store chunk NCH-1.
            const int pb = (NCH - 1) & 1;
            const int o4 = slab4 + (NCH - 1) * CHUNK_F4 + tid;
            const f32x4 r0 = *(const f32x4*)&s_out[pb][4 * tid];
            const f32x4 r1 = *(const f32x4*)&s_out[pb][4 * (tid + 256)];
            __builtin_nontemporal_store(r0, &gout[o4]);
            __builtin_nontemporal_store(r1, &gout[o4 + 256]);
        }
    } else {
        // ---------- partial slab: simple guarded path, all 512 threads ----------
        for (int k = 0; k < NCH; ++k) {
            const int idx = slab4 + k * CHUNK_F4 + tid;   // tid in [0,512)
            if (idx < n4 && tid < CHUNK_F4) {
                const f32x4 A = gin[idx];
                f32x4 oA;
                EVAL4(A, oA)
                __builtin_nontemporal_store(oA, &gout[idx]);
            }
        }
        // cover the second half of each chunk (threads 0..511 do 16 f4 each)
        for (int k = 0; k < NCH; ++k) {
            const int idx = slab4 + k * CHUNK_F4 + 512 + (tid - 512);
            (void)idx; // layout note: CHUNK_F4=512 == blockDim, loop above suffices
        }
    }
    // Scalar tail (n % 4), block 0.
    if (blockIdx.x == 0) {
        const int rem = n & 3;
        if (tid < rem) {
            const float r = w[(n4 << 2) + tid];
            float d;
            EVAL(r, d)
            out[(n4 << 2) + tid] = d;
        }
    }
#undef EVAL4
#undef EVAL
#undef TERM
}

extern "C" void kernel_launch(void* const* d_in, const int* in_sizes, int n_in,
                              void* d_out, int out_size, void* d_ws, size_t ws_size,
                              hipStream_t stream) {
    const float* w   = (const float*)d_in[0];
    const float* cs  = (const float*)d_in[1];
    const float* fs  = (const float*)d_in[2];
    const float* W1  = (const float*)d_in[3];
    const float* b1  = (const float*)d_in[4];
    const float* W2  = (const float*)d_in[5];
    const float* b2  = (const float*)d_in[6];
    float* out = (float*)d_out;

    const int n  = in_sizes[0];
    const int n4 = n >> 2;
    // 512-thread blocks; each owns 8192 float4 (128KB in). n=4096^2 -> 512
    // blocks = 2 blocks/CU = 16 waves/CU (8 MEM + 8 CMP per CU).
    const int block = 512;
    int grid = (n4 + SLAB_F4 - 1) / SLAB_F4;
    if (grid < 1) grid = 1;

    ConsolidationDynamics_70068096467285_kernel<<<grid, block, 0, stream>>>(
        w, cs, fs, W1, b1, W2, b2, out, n);
}